// Round 9
// baseline (256.543 us; speedup 1.0000x reference)
//
#include <hip/hip_runtime.h>
#include <hip/hip_fp16.h>
#include <stdint.h>

typedef int i32x4 __attribute__((ext_vector_type(4)));

#define BM 128
#define BN 256
#define BKB 128           // K-bytes (= int8 elems) per tile
#define NSLOT 3
#define SLOT_BYTES 49152  // A 16KB + B 32KB per slot; 3 slots = 144KB
#define THREADS 512

__device__ __forceinline__ void gload_lds16(const void* g, void* l) {
  __builtin_amdgcn_global_load_lds(
      (const __attribute__((address_space(1))) unsigned int*)g,
      (__attribute__((address_space(3))) unsigned int*)l, 16, 0, 0);
}

// ---------------- quantize x: fp32(fp16 values) -> int8, grid-stride --------
__global__ __launch_bounds__(256) void quant_x_kernel(
    const float* __restrict__ x, const float* __restrict__ deltap,
    const float* __restrict__ zpp, int8_t* __restrict__ q, int n16) {
  const float rdelta = 1.0f / deltap[0];
  const float zp = zpp[0];
  for (int i = blockIdx.x * blockDim.x + threadIdx.x; i < n16;
       i += gridDim.x * blockDim.x) {
    const float4* src = (const float4*)x + (size_t)i * 4;
    int packed[4];
#pragma unroll
    for (int g = 0; g < 4; ++g) {
      float4 v = src[g];
      float f0 = fminf(127.f, fmaxf(-128.f, rintf(fmaf(v.x, rdelta, zp))));
      float f1 = fminf(127.f, fmaxf(-128.f, rintf(fmaf(v.y, rdelta, zp))));
      float f2 = fminf(127.f, fmaxf(-128.f, rintf(fmaf(v.z, rdelta, zp))));
      float f3 = fminf(127.f, fmaxf(-128.f, rintf(fmaf(v.w, rdelta, zp))));
      int q0 = (int)f0 & 255, q1 = (int)f1 & 255, q2 = (int)f2 & 255, q3 = (int)f3 & 255;
      packed[g] = q0 | (q1 << 8) | (q2 << 16) | (q3 << 24);
    }
    ((int4*)q)[i] = make_int4(packed[0], packed[1], packed[2], packed[3]);
  }
}

// ---------------- pack W: int32 -> int8, 16 elems/thread --------------------
__global__ __launch_bounds__(256) void pack_w_kernel(
    const int* __restrict__ w, int8_t* __restrict__ wp, int n16) {
  int i = blockIdx.x * blockDim.x + threadIdx.x;
  if (i >= n16) return;
  const int4* src = (const int4*)w + (size_t)i * 4;
  int packed[4];
#pragma unroll
  for (int g = 0; g < 4; ++g) {
    int4 v = src[g];
    packed[g] = (v.x & 255) | ((v.y & 255) << 8) | ((v.z & 255) << 16) | ((v.w & 255) << 24);
  }
  ((int4*)wp)[i] = make_int4(packed[0], packed[1], packed[2], packed[3]);
}

// ---------------- int8 GEMM, 128x256 tile, reg-dbuf fragment pipeline -------
// 8 waves (2M x 4N), wave-tile 64x64, acc[4][4] i32x4, 2 frag sets (~230 VGPR
// -> 2 waves/SIMD). Iter t: stage(t+2) | vmcnt(6) lgkm(0) BAR | READF(t+1,
// other set) | MFMA(t, current set). MFMA has no reg-dep on the just-issued
// reads -> LDS pipe and matrix pipe overlap; compiler emits counted lgkm
// before next iter's MFMA. 3-slot ledger: regs=t, reads=t+1, DMA=t+2.
// lgkm(0)-before-BAR makes READF(t) provably done before stage(t+3)
// overwrites slot t%3. T2 chunk-XOR swizzle (0 conflicts r2-r8) + T1 XCD.
__global__ __launch_bounds__(THREADS, 2) void gemm_i8_kernel(
    const int8_t* __restrict__ Aq, const int8_t* __restrict__ Bw,
    const float* __restrict__ atwd, const float* __restrict__ zpws,
    const float* __restrict__ bias, float* __restrict__ out,
    int Mc, int Nc, int Kc) {
  __shared__ int8_t lds[NSLOT * SLOT_BYTES];

  // ---- T1 bijective XCD swizzle (nwg multiple of 8 here) ----
  const int nwg = gridDim.x;
  int bid = blockIdx.x;
  if ((nwg & 7) == 0) bid = (bid & 7) * (nwg >> 3) + (bid >> 3);
  const int nbn = Nc / BN;
  const int bm = bid / nbn;
  const int bn = bid % nbn;

  const int tid = threadIdx.x;
  const size_t K = (size_t)Kc;
  const int NT = Kc / BKB;

  // ---- staging: sweep = 512 thr x 16B = 8KB = 64 rows x 128B ----
  const int srow = tid >> 3;                        // 0..63
  const int cs = tid & 7;                           // storage chunk
  const int cl = cs ^ (srow & 7);                   // inverse-swizzled source
  const int8_t* gA = Aq + ((size_t)(bm * BM + srow)) * K + cl * 16;
  const int8_t* gB = Bw + ((size_t)(bn * BN + srow)) * K + cl * 16;
  const size_t row64 = (size_t)64 * K;
  int8_t* ldst = &lds[tid * 16];

  auto stage = [&](int t, int slot) {   // 6 gloads: A 2x8KB, B 4x8KB
    int8_t* l = ldst + slot * SLOT_BYTES;
    const size_t koff = (size_t)t * BKB;
#pragma unroll
    for (int r = 0; r < 2; ++r)
      gload_lds16(gA + koff + r * row64, l + r * 8192);
#pragma unroll
    for (int r = 0; r < 4; ++r)
      gload_lds16(gB + koff + r * row64, l + 16384 + r * 8192);
  };

  // ---- fragment geometry: 8 waves 2x4, wave-tile 64x64 ----
  const int lane = tid & 63;
  const int wave = tid >> 6;
  const int wr = wave >> 2;          // 0..1 -> 64-row halves of BM=128
  const int wc = wave & 3;           // 0..3 -> 64-col strips of BN=256
  const int fr = lane & 15;
  const int kc = lane >> 4;          // 16B chunk within K-half
  const int swz = fr & 7;
  const int aRow = wr * 64 + fr;
  const int bRow = wc * 64 + fr;

  i32x4 acc[4][4] = {};
  i32x4 fa0[4][2], fb0[4][2], fa1[4][2], fb1[4][2];

#define READF(AF, BF, t)                                                      \
  {                                                                           \
    const int8_t* sA_ = &lds[((t) % NSLOT) * SLOT_BYTES];                     \
    const int8_t* sB_ = sA_ + 16384;                                          \
    _Pragma("unroll") for (int ks_ = 0; ks_ < 2; ++ks_) {                     \
      const int co_ = ((ks_ * 4 + kc) ^ swz) << 4;                            \
      _Pragma("unroll") for (int i_ = 0; i_ < 4; ++i_)                        \
        AF[i_][ks_] = *(const i32x4*)&sA_[(aRow + i_ * 16) * 128 + co_];      \
      _Pragma("unroll") for (int j_ = 0; j_ < 4; ++j_)                        \
        BF[j_][ks_] = *(const i32x4*)&sB_[(bRow + j_ * 16) * 128 + co_];      \
    }                                                                         \
  }

#define DOMFMA(AF, BF)                                                        \
  _Pragma("unroll") for (int ks_ = 0; ks_ < 2; ++ks_)                         \
    _Pragma("unroll") for (int i_ = 0; i_ < 4; ++i_)                          \
      _Pragma("unroll") for (int j_ = 0; j_ < 4; ++j_)                        \
        acc[i_][j_] = __builtin_amdgcn_mfma_i32_16x16x64_i8(                  \
            AF[i_][ks_], BF[j_][ks_], acc[i_][j_], 0, 0, 0);

#define SYNCN(N)                                                              \
  asm volatile("s_waitcnt vmcnt(" #N ")" ::: "memory");                       \
  asm volatile("s_waitcnt lgkmcnt(0)" ::: "memory");                          \
  __builtin_amdgcn_s_barrier();                                               \
  __builtin_amdgcn_sched_barrier(0);

  // ---- prologue: stage tiles 0,1; drain DMA(0); read frags(0) -> set0 ----
  stage(0, 0);
  stage(1, 1);
  SYNCN(6);
  READF(fa0, fb0, 0);

  for (int t = 0; t < NT; t += 2) {
    // -- even half: compute tile t (set0), prefetch frags(t+1) -> set1 --
    if (t + 2 < NT) stage(t + 2, (t + 2) % NSLOT);
    if (t + 2 < NT) { SYNCN(6); } else { SYNCN(0); }
    if (t + 1 < NT) READF(fa1, fb1, t + 1);
    DOMFMA(fa0, fb0);

    // -- odd half: compute tile t+1 (set1), prefetch frags(t+2) -> set0 --
    if (t + 3 < NT) stage(t + 3, (t + 3) % NSLOT);
    if (t + 3 < NT)      { SYNCN(6); }
    else if (t + 2 < NT) { SYNCN(0); }
    if (t + 2 < NT) READF(fa0, fb0, t + 2);
    if (t + 1 < NT) DOMFMA(fa1, fb1);
  }
#undef READF
#undef DOMFMA
#undef SYNCN

  // ---- epilogue: C/D col=lane&15, row=(lane>>4)*4+reg; j-innermost ----
  const int r4 = (lane >> 4) << 2;
  const int cn0 = bn * BN + wc * 64 + fr;
  float aw4[4], zs4[4], bs4[4];
#pragma unroll
  for (int j = 0; j < 4; ++j) {
    aw4[j] = atwd[cn0 + j * 16];
    zs4[j] = zpws[cn0 + j * 16];
    bs4[j] = bias[cn0 + j * 16];
  }
#pragma unroll
  for (int mi = 0; mi < 4; ++mi) {
#pragma unroll
    for (int r = 0; r < 4; ++r) {
      const size_t rbase = (size_t)(bm * BM + wr * 64 + mi * 16 + r4 + r) * (size_t)Nc;
#pragma unroll
      for (int j = 0; j < 4; ++j) {
        float v = (float)acc[mi][j][r] * aw4[j] - zs4[j] + bs4[j];
        v = __half2float(__float2half(v));  // match fp16 output rounding
        out[rbase + cn0 + j * 16] = v;
      }
    }
  }
}

extern "C" void kernel_launch(void* const* d_in, const int* in_sizes, int n_in,
                              void* d_out, int out_size, void* d_ws, size_t ws_size,
                              hipStream_t stream) {
  const float* x         = (const float*)d_in[0];
  const float* act_delta = (const float*)d_in[1];
  const float* act_zp    = (const float*)d_in[2];
  const float* zpws      = (const float*)d_in[3];
  const float* atwd      = (const float*)d_in[4];
  const float* bias      = (const float*)d_in[5];
  const int*   w32       = (const int*)d_in[6];
  float* out = (float*)d_out;

  const int N = in_sizes[5];
  const int K = in_sizes[6] / N;
  const int M = in_sizes[0] / K;

  int8_t* q  = (int8_t*)d_ws;               // M*K bytes
  int8_t* wp = q + (size_t)M * K;           // N*K bytes

  {
    int n16 = (M * K) / 16;
    int grid = (n16 + 255) / 256;
    if (grid > 2048) grid = 2048;
    quant_x_kernel<<<grid, 256, 0, stream>>>(x, act_delta, act_zp, q, n16);
  }
  {
    int n16 = (N * K) / 16;
    pack_w_kernel<<<(n16 + 255) / 256, 256, 0, stream>>>(w32, wp, n16);
  }
  {
    dim3 grid((M / BM) * (N / BN));
    gemm_i8_kernel<<<grid, THREADS, 0, stream>>>(q, wp, atwd, zpws, bias, out, M, N, K);
  }
}

// Round 10
// 255.533 us; speedup vs baseline: 1.0040x; 1.0040x over previous
//
#include <hip/hip_runtime.h>
#include <hip/hip_fp16.h>
#include <stdint.h>

typedef int i32x4 __attribute__((ext_vector_type(4)));
typedef int i32x16 __attribute__((ext_vector_type(16)));

#define BM 256
#define BN 256
#define BKB 128           // K-bytes (= int8 elems) per tile
#define SLOT 65536        // A 32KB + B 32KB per slot, 2 slots = 128KB
#define THREADS 512

__device__ __forceinline__ void gload_lds16(const void* g, void* l) {
  __builtin_amdgcn_global_load_lds(
      (const __attribute__((address_space(1))) unsigned int*)g,
      (__attribute__((address_space(3))) unsigned int*)l, 16, 0, 0);
}

// ---------------- quantize x: fp32(fp16 values) -> int8, grid-stride --------
__global__ __launch_bounds__(256) void quant_x_kernel(
    const float* __restrict__ x, const float* __restrict__ deltap,
    const float* __restrict__ zpp, int8_t* __restrict__ q, int n16) {
  const float rdelta = 1.0f / deltap[0];
  const float zp = zpp[0];
  for (int i = blockIdx.x * blockDim.x + threadIdx.x; i < n16;
       i += gridDim.x * blockDim.x) {
    const float4* src = (const float4*)x + (size_t)i * 4;
    int packed[4];
#pragma unroll
    for (int g = 0; g < 4; ++g) {
      float4 v = src[g];
      float f0 = fminf(127.f, fmaxf(-128.f, rintf(fmaf(v.x, rdelta, zp))));
      float f1 = fminf(127.f, fmaxf(-128.f, rintf(fmaf(v.y, rdelta, zp))));
      float f2 = fminf(127.f, fmaxf(-128.f, rintf(fmaf(v.z, rdelta, zp))));
      float f3 = fminf(127.f, fmaxf(-128.f, rintf(fmaf(v.w, rdelta, zp))));
      int q0 = (int)f0 & 255, q1 = (int)f1 & 255, q2 = (int)f2 & 255, q3 = (int)f3 & 255;
      packed[g] = q0 | (q1 << 8) | (q2 << 16) | (q3 << 24);
    }
    ((int4*)q)[i] = make_int4(packed[0], packed[1], packed[2], packed[3]);
  }
}

// ---------------- pack W: int32 -> int8, 16 elems/thread --------------------
__global__ __launch_bounds__(256) void pack_w_kernel(
    const int* __restrict__ w, int8_t* __restrict__ wp, int n16) {
  int i = blockIdx.x * blockDim.x + threadIdx.x;
  if (i >= n16) return;
  const int4* src = (const int4*)w + (size_t)i * 4;
  int packed[4];
#pragma unroll
  for (int g = 0; g < 4; ++g) {
    int4 v = src[g];
    packed[g] = (v.x & 255) | ((v.y & 255) << 8) | ((v.z & 255) << 16) | ((v.w & 255) << 24);
  }
  ((int4*)wp)[i] = make_int4(packed[0], packed[1], packed[2], packed[3]);
}

// ---------------- int8 GEMM, 256x256 tile, 32x32x32 MFMA --------------------
// r8 frame (proven ledger: 2-slot dbuf, stage(t+1) inside tile, vmcnt(0)+
// barrier at tile end) with ONE variable changed: MFMA shape 16x16x64 ->
// 32x32x32. 4x fewer MFMA instructions (256 vs 1024 per CU-tile) at +12%
// rate. 8 waves (2M x 4N), wave-tile 128x64: A-frags f=0..3 (rows f*32),
// B-frags j=0..1 (cols j*32), 4 K-steps of 32. acc[4][2] i32x16 = 128 VGPR,
// __launch_bounds__(512,2) -> 2 waves/SIMD.
// Swizzle re-derived for 32-row fragments: storage chunk = logical ^
// ((row>>1)&7)  (8 chunks of 16B per 128-B row); 16-lane even/odd row groups
// spread over all 8 chunks -> 2 lanes/bank (free). Inverse on global source.
__global__ __launch_bounds__(THREADS, 2) void gemm_i8_kernel(
    const int8_t* __restrict__ Aq, const int8_t* __restrict__ Bw,
    const float* __restrict__ atwd, const float* __restrict__ zpws,
    const float* __restrict__ bias, float* __restrict__ out,
    int Mc, int Nc, int Kc) {
  __shared__ int8_t lds[2 * SLOT];

  // ---- T1 bijective XCD swizzle (nwg multiple of 8 here) ----
  const int nwg = gridDim.x;
  int bid = blockIdx.x;
  if ((nwg & 7) == 0) bid = (bid & 7) * (nwg >> 3) + (bid >> 3);
  const int nbn = Nc / BN;
  const int bm = bid / nbn;
  const int bn = bid % nbn;

  const int tid = threadIdx.x;
  const size_t K = (size_t)Kc;
  const int NT = Kc / BKB;

  // ---- staging: sweep = 512 thr x 16B = 8KB = 64 rows x 128B ----
  const int srow = tid >> 3;                        // 0..63
  const int cs = tid & 7;                           // storage chunk
  const int cl = cs ^ ((srow >> 1) & 7);            // inverse-swizzled source
  const int8_t* gA = Aq + ((size_t)(bm * BM + srow)) * K + cl * 16;
  const int8_t* gB = Bw + ((size_t)(bn * BN + srow)) * K + cl * 16;
  const size_t row64 = (size_t)64 * K;
  int8_t* ldst = &lds[tid * 16];

  auto stage = [&](int t, int slot) {   // 8 gloads: A 4x8KB, B 4x8KB
    int8_t* l = ldst + slot * SLOT;
    const size_t koff = (size_t)t * BKB;
#pragma unroll
    for (int r = 0; r < 4; ++r)
      gload_lds16(gA + koff + r * row64, l + r * 8192);
#pragma unroll
    for (int r = 0; r < 4; ++r)
      gload_lds16(gB + koff + r * row64, l + 32768 + r * 8192);
  };

  // ---- fragment geometry: 8 waves 2x4, wave-tile 128x64, 32x32x32 ----
  const int lane = tid & 63;
  const int wave = tid >> 6;
  const int wr = wave >> 2;          // 0..1 -> 128-row halves
  const int wc = wave & 3;           // 0..3 -> 64-col strips
  const int fr32 = lane & 31;
  const int kh2 = lane >> 5;         // which 16B within the 32B K-step
  const int swz = (fr32 >> 1) & 7;
  const int aRow = wr * 128 + fr32;
  const int bRow = wc * 64 + fr32;

  i32x16 acc[4][2] = {};

  // ---- prologue ----
  stage(0, 0);
  asm volatile("s_waitcnt vmcnt(0)" ::: "memory");
  __builtin_amdgcn_s_barrier();
  __builtin_amdgcn_sched_barrier(0);

  for (int t = 0; t < NT; ++t) {
    const int8_t* sA = &lds[(t & 1) * SLOT];
    const int8_t* sB = sA + 32768;

    i32x4 af[4][4], bf[2][4];   // [frag][ks]
#pragma unroll
    for (int ks = 0; ks < 4; ++ks) {
      const int co = ((2 * ks + kh2) ^ swz) << 4;
#pragma unroll
      for (int f = 0; f < 4; ++f)
        af[f][ks] = *(const i32x4*)&sA[(aRow + f * 32) * 128 + co];
#pragma unroll
      for (int j = 0; j < 2; ++j)
        bf[j][ks] = *(const i32x4*)&sB[(bRow + j * 32) * 128 + co];
    }

    if (t + 1 < NT) stage(t + 1, (t + 1) & 1);

#pragma unroll
    for (int ks = 0; ks < 4; ++ks)
#pragma unroll
      for (int f = 0; f < 4; ++f)
#pragma unroll
        for (int j = 0; j < 2; ++j)
          acc[f][j] = __builtin_amdgcn_mfma_i32_32x32x32_i8(
              af[f][ks], bf[j][ks], acc[f][j], 0, 0, 0);

    // ---- tile boundary: U(t+1) landed, collective barrier ----
    if (t < NT - 1) {
      asm volatile("s_waitcnt vmcnt(0)" ::: "memory");
      __builtin_amdgcn_s_barrier();
      __builtin_amdgcn_sched_barrier(0);
    }
  }

  // ---- epilogue: 32x32 C/D (r7-verified): col=lane&31,
  // row=(reg&3)+8*(reg>>2)+4*(lane>>5). Lanes 0-31 cover 128B contiguous.
  const int cn0 = bn * BN + wc * 64 + fr32;
  float aw[2], zs[2], bs[2];
#pragma unroll
  for (int j = 0; j < 2; ++j) {
    aw[j] = atwd[cn0 + j * 32];
    zs[j] = zpws[cn0 + j * 32];
    bs[j] = bias[cn0 + j * 32];
  }
  const int rbase0 = bm * BM + wr * 128 + 4 * kh2;
#pragma unroll
  for (int f = 0; f < 4; ++f) {
#pragma unroll
    for (int reg = 0; reg < 16; ++reg) {
      const int rloc = (reg & 3) + 8 * (reg >> 2);
      const size_t rbase = (size_t)(rbase0 + f * 32 + rloc) * (size_t)Nc;
#pragma unroll
      for (int j = 0; j < 2; ++j) {
        float v = (float)acc[f][j][reg] * aw[j] - zs[j] + bs[j];
        v = __half2float(__float2half(v));  // match fp16 output rounding
        out[rbase + cn0 + j * 32] = v;
      }
    }
  }
}

extern "C" void kernel_launch(void* const* d_in, const int* in_sizes, int n_in,
                              void* d_out, int out_size, void* d_ws, size_t ws_size,
                              hipStream_t stream) {
  const float* x         = (const float*)d_in[0];
  const float* act_delta = (const float*)d_in[1];
  const float* act_zp    = (const float*)d_in[2];
  const float* zpws      = (const float*)d_in[3];
  const float* atwd      = (const float*)d_in[4];
  const float* bias      = (const float*)d_in[5];
  const int*   w32       = (const int*)d_in[6];
  float* out = (float*)d_out;

  const int N = in_sizes[5];
  const int K = in_sizes[6] / N;
  const int M = in_sizes[0] / K;

  int8_t* q  = (int8_t*)d_ws;               // M*K bytes
  int8_t* wp = q + (size_t)M * K;           // N*K bytes

  {
    int n16 = (M * K) / 16;
    int grid = (n16 + 255) / 256;
    if (grid > 2048) grid = 2048;
    quant_x_kernel<<<grid, 256, 0, stream>>>(x, act_delta, act_zp, q, n16);
  }
  {
    int n16 = (N * K) / 16;
    pack_w_kernel<<<(n16 + 255) / 256, 256, 0, stream>>>(w32, wp, n16);
  }
  {
    dim3 grid((M / BM) * (N / BN));
    gemm_i8_kernel<<<grid, THREADS, 0, stream>>>(q, wp, atwd, zpws, bias, out, M, N, K);
  }
}